// Round 4
// baseline (27140.509 us; speedup 1.0000x reference)
//
#include <hip/hip_runtime.h>
#include <hip/hip_bf16.h>

typedef __hip_bfloat16 bf16;
typedef unsigned long long u64;
typedef unsigned int u32;
typedef unsigned short u16;
using short8 = __attribute__((ext_vector_type(8))) short;   // 8 bf16 MFMA A/B frag
using f32x4  = __attribute__((ext_vector_type(4))) float;   // MFMA C/D frag

#define T_STEPS 2048
#define IDIM    256
#define HDIM    512
#define NBLK    32                // fused: each block owns a 16-unit slice of BOTH layers
#define RS0     4                 // h0 ring slots
#define HWW     8192              // u32 words per h buffer: [16 batch-pairs][512 units]
#define LROW    528               // LDS row stride (bf16 elems); 1056B == 8 dw mod 32

__device__ __forceinline__ float sigm(float x) { return 1.0f / (1.0f + __expf(-x)); }
__device__ __forceinline__ float tanh_f(float x) {
  x = fminf(fmaxf(x, -15.f), 15.f);
  float e = __expf(2.f * x);
  return (e - 1.f) / (e + 1.f);
}
__device__ __forceinline__ u16 bfbits(float f) {
  bf16 b = __float2bfloat16(f); u16 s; __builtin_memcpy(&s, &b, 2); return s;
}
__device__ __forceinline__ short8 cvt8(const float* __restrict__ p) {
  float4 lo = *(const float4*)(const void*)p;
  float4 hi = *(const float4*)(const void*)(p + 4);
  short8 r;
  r[0] = (short)bfbits(lo.x); r[1] = (short)bfbits(lo.y); r[2] = (short)bfbits(lo.z); r[3] = (short)bfbits(lo.w);
  r[4] = (short)bfbits(hi.x); r[5] = (short)bfbits(hi.y); r[6] = (short)bfbits(hi.z); r[7] = (short)bfbits(hi.w);
  return r;
}

// LLC-coherent (L1/L2-bypassing) accesses: agent-scope atomics.
__device__ __forceinline__ u64 ldg8(const u64* p) {
  return __hip_atomic_load(p, __ATOMIC_RELAXED, __HIP_MEMORY_SCOPE_AGENT);
}
__device__ __forceinline__ u32 ldg4(const u32* p) {
  return __hip_atomic_load(p, __ATOMIC_RELAXED, __HIP_MEMORY_SCOPE_AGENT);
}
__device__ __forceinline__ void stg4(u32* p, u32 v) {
  __hip_atomic_store(p, v, __ATOMIC_RELAXED, __HIP_MEMORY_SCOPE_AGENT);
}
__device__ __forceinline__ void stg_rel(u32* p, u32 v) {
  __hip_atomic_store(p, v, __ATOMIC_RELEASE, __HIP_MEMORY_SCOPE_AGENT);
}

// Per-wave store drain: stores are at LLC (globally visible) once vmcnt==0.
#define DRAIN() asm volatile("s_waitcnt vmcnt(0)" ::: "memory")
#define ACQ_FENCE() __builtin_amdgcn_fence(__ATOMIC_ACQUIRE, "agent")

__device__ __forceinline__ int wave_min_i(int v) {
#pragma unroll
  for (int off = 32; off > 0; off >>= 1) {
    int o = __shfl_xor(v, off, 64);
    v = v < o ? v : o;
  }
  return v;
}

// Spin until min over the 32 combined per-block flags >= target.
__device__ __forceinline__ void wait_all(const u32* __restrict__ f, u32 target, int lane) {
  for (;;) {
    int v = (int)ldg4(f + (lane & 31));
    if (wave_min_i(v) >= (int)target) return;
  }
}

// Single-pass stage of one 32KB h buffer (u32 word w: lo16 = h[w>>9][w&511],
// hi16 = h[(w>>9)+16][w&511]) into LDS [32][LROW] bf16. 256 thr x 16 u64 chunks.
__device__ __forceinline__ void stage_data(const u32* __restrict__ src, bf16* dst, int tid) {
  const u64* s = (const u64*)(const void*)src;
  u64 v[16];
#pragma unroll
  for (int i = 0; i < 16; i++) v[i] = ldg8(s + tid + i * 256);
  const int col = tid * 2;
#pragma unroll
  for (int i = 0; i < 16; i++) {
    u32 lo = (u32)v[i], hi = (u32)(v[i] >> 32);
    *(u32*)(void*)(dst + i * LROW + col)        = (lo & 0xffffu) | (hi << 16);
    *(u32*)(void*)(dst + (i + 16) * LROW + col) = (lo >> 16) | (hi & 0xffff0000u);
  }
}

#define MFMA(a, b, c) __builtin_amdgcn_mfma_f32_16x16x32_bf16((a), (b), (c), 0, 0, 0)

__global__ void __launch_bounds__(256, 1) lstm_fused(
    const float* __restrict__ x,
    const float* __restrict__ Wih0, const float* __restrict__ Whh0,
    const float* __restrict__ bih0, const float* __restrict__ bhh0,
    const float* __restrict__ Wih1, const float* __restrict__ Whh1,
    const float* __restrict__ bih1, const float* __restrict__ bhh1,
    const float* __restrict__ fcw, const float* __restrict__ fcb,
    float* __restrict__ out,
    u32* __restrict__ flg,         // 32 combined per-block flags: f[b]=p+1 <=>
                                   //   "block b's h0[p] AND h1[p-1] are at LLC"
    u32* __restrict__ ring0,       // RS0 x HWW packed bf16-pair words (h0)
    u32* __restrict__ ring1) {     // 2   x HWW (h1)
  __shared__ __align__(16) bf16 lds_h0[32 * LROW];
  __shared__ __align__(16) bf16 lds_h1[32 * LROW];

  const int tid  = threadIdx.x;
  const int w    = tid >> 6, lane = tid & 63;
  const int q    = lane >> 4, m = lane & 15, q8 = q * 8;
  const int bx   = (int)blockIdx.x;
  const int jb   = bx * 16 + w * 4;
  const int unit = jb + (m >> 2), gate = m & 3;
  const int wrow = gate * HDIM + unit;
  const int ju   = jb + q;
  const f32x4 zero = {0.f, 0.f, 0.f, 0.f};

  // ---- Preload BOTH layers' weights (f32 -> bf16 A-frags) into VGPRs ----
  short8 Ax0[8], Ah0[16], Ax1[16], Ah1[16];
  f32x4 bias0, bias1;
#pragma unroll
  for (int kc = 0; kc < 8; kc++)  Ax0[kc] = cvt8(Wih0 + wrow * IDIM + kc * 32 + q8);
#pragma unroll
  for (int kc = 0; kc < 16; kc++) Ah0[kc] = cvt8(Whh0 + wrow * HDIM + kc * 32 + q8);
#pragma unroll
  for (int kc = 0; kc < 16; kc++) Ax1[kc] = cvt8(Wih1 + wrow * HDIM + kc * 32 + q8);
#pragma unroll
  for (int kc = 0; kc < 16; kc++) Ah1[kc] = cvt8(Whh1 + wrow * HDIM + kc * 32 + q8);
#pragma unroll
  for (int r = 0; r < 4; r++) {
    bias0[r] = bih0[r * HDIM + ju] + bhh0[r * HDIM + ju];
    bias1[r] = bih1[r * HDIM + ju] + bhh1[r * HDIM + ju];
  }

  float c0a = 0.f, c0b = 0.f, c1a = 0.f, c1b = 0.f;

  // prefetch xg[0]
  f32x4 an0 = bias0, an1 = bias0;
  {
    const float* xa = x + (size_t)m * (T_STEPS * IDIM) + q8;
    const float* xb = xa + (size_t)16 * (T_STEPS * IDIM);
#pragma unroll
    for (int kc = 0; kc < 8; kc++) {
      an0 = MFMA(Ax0[kc], cvt8(xa + kc * 32), an0);
      an1 = MFMA(Ax0[kc], cvt8(xb + kc * 32), an1);
    }
  }

  for (int p = 0; p < T_STEPS; ++p) {
    // ---- (1) layer-0 cell: gates = xg[p] + Whh0 * h0[p-1] (lds_h0, staged last iter)
    f32x4 a0 = an0, a1 = an1;
    if (p > 0) {
      f32x4 b0 = zero, b1 = zero;                     // split chains: 4 deep-8 pipes
#pragma unroll
      for (int kc = 0; kc < 8; kc++) {
        short8 r0 = *(const short8*)(const void*)(lds_h0 + m * LROW + kc * 32 + q8);
        short8 r1 = *(const short8*)(const void*)(lds_h0 + (m + 16) * LROW + kc * 32 + q8);
        a0 = MFMA(Ah0[kc], r0, a0);
        a1 = MFMA(Ah0[kc], r1, a1);
        short8 s0 = *(const short8*)(const void*)(lds_h0 + m * LROW + (kc + 8) * 32 + q8);
        short8 s1 = *(const short8*)(const void*)(lds_h0 + (m + 16) * LROW + (kc + 8) * 32 + q8);
        b0 = MFMA(Ah0[kc + 8], s0, b0);
        b1 = MFMA(Ah0[kc + 8], s1, b1);
      }
      a0 = a0 + b0; a1 = a1 + b1;
    }
    {
      float ia = sigm(a0[0]), fa = sigm(a0[1]), ga = tanh_f(a0[2]), oa = sigm(a0[3]);
      c0a = fa * c0a + ia * ga;
      float ib = sigm(a1[0]), fb = sigm(a1[1]), gb = tanh_f(a1[2]), ob = sigm(a1[3]);
      c0b = fb * c0b + ib * gb;
      u32 pack = (u32)bfbits(oa * tanh_f(c0a)) | ((u32)bfbits(ob * tanh_f(c0b)) << 16);
      // ---- (2) publish h0[p]; the DRAIN also retires last iter's h1 stores,
      //      so ONE release/step covers both buffers.
      stg4(ring0 + (p & (RS0 - 1)) * HWW + (m << 9) + ju, pack);
    }
    DRAIN();
    __syncthreads();
    if (tid == 0) stg_rel(flg + bx, (u32)(p + 1));

    // ---- (2b) stage h1[p-1]: visibility was established by LAST step's wait
    //      (f >= p covers h1[p-1]) -> NO wait here; fully off the critical path.
    if (p > 0) stage_data(ring1 + ((p - 1) & 1) * HWW, lds_h1, tid);

    // ---- (7) xg[p+1] prefetch, hidden under release propagation / stragglers
    if (p + 1 < T_STEPS) {
      an0 = bias0; an1 = bias0;
      const float* xa = x + (size_t)m * (T_STEPS * IDIM) + (size_t)(p + 1) * IDIM + q8;
      const float* xb = xa + (size_t)16 * (T_STEPS * IDIM);
#pragma unroll
      for (int kc = 0; kc < 8; kc++) {
        an0 = MFMA(Ax0[kc], cvt8(xa + kc * 32), an0);
        an1 = MFMA(Ax0[kc], cvt8(xb + kc * 32), an1);
      }
    }

    // ---- (3) the ONLY rendezvous: all blocks' h0[p] at LLC
    wait_all(flg, (u32)(p + 1), lane);
    ACQ_FENCE();
    // ---- (4) stage h0[p]; serves BOTH this step's Wih1 and next step's Whh0
    stage_data(ring0 + (p & (RS0 - 1)) * HWW, lds_h0, tid);
    __syncthreads();

    // ---- (5) layer-1 cell: gates = Wih1*h0[p] + Whh1*h1[p-1]
    {
      f32x4 g0 = bias1, g1 = bias1, p0 = zero, p1 = zero;
#pragma unroll
      for (int kc = 0; kc < 8; kc++) {
        short8 r0 = *(const short8*)(const void*)(lds_h0 + m * LROW + kc * 32 + q8);
        short8 r1 = *(const short8*)(const void*)(lds_h0 + (m + 16) * LROW + kc * 32 + q8);
        g0 = MFMA(Ax1[kc], r0, g0);
        g1 = MFMA(Ax1[kc], r1, g1);
        short8 s0 = *(const short8*)(const void*)(lds_h0 + m * LROW + (kc + 8) * 32 + q8);
        short8 s1 = *(const short8*)(const void*)(lds_h0 + (m + 16) * LROW + (kc + 8) * 32 + q8);
        p0 = MFMA(Ax1[kc + 8], s0, p0);
        p1 = MFMA(Ax1[kc + 8], s1, p1);
      }
      if (p > 0) {
#pragma unroll
        for (int kc = 0; kc < 8; kc++) {
          short8 r0 = *(const short8*)(const void*)(lds_h1 + m * LROW + kc * 32 + q8);
          short8 r1 = *(const short8*)(const void*)(lds_h1 + (m + 16) * LROW + kc * 32 + q8);
          g0 = MFMA(Ah1[kc], r0, g0);
          g1 = MFMA(Ah1[kc], r1, g1);
          short8 s0 = *(const short8*)(const void*)(lds_h1 + m * LROW + (kc + 8) * 32 + q8);
          short8 s1 = *(const short8*)(const void*)(lds_h1 + (m + 16) * LROW + (kc + 8) * 32 + q8);
          p0 = MFMA(Ah1[kc + 8], s0, p0);
          p1 = MFMA(Ah1[kc + 8], s1, p1);
        }
      }
      g0 = g0 + p0; g1 = g1 + p1;
      float ia = sigm(g0[0]), fa = sigm(g0[1]), ga = tanh_f(g0[2]), oa = sigm(g0[3]);
      c1a = fa * c1a + ia * ga;
      float ib = sigm(g1[0]), fb = sigm(g1[1]), gb = tanh_f(g1[2]), ob = sigm(g1[3]);
      c1b = fb * c1b + ib * gb;
      u32 pack = (u32)bfbits(oa * tanh_f(c1a)) | ((u32)bfbits(ob * tanh_f(c1b)) << 16);
      // ---- (6) store h1[p]; drain deferred into next step's (2) release
      stg4(ring1 + (p & 1) * HWW + (m << 9) + ju, pack);
    }
    // Next iter (1) reads lds_h0 = h0[p], staged at (4) behind a barrier. Safe.
  }

  // ---- final publish: h1[T-1] stores drained + released as f = T+1
  DRAIN();
  __syncthreads();
  if (tid == 0) stg_rel(flg + bx, (u32)(T_STEPS + 1));

  // ---- FC epilogue on blocks 0..15 ----
  if (bx < 16) {
    wait_all(flg, (u32)(T_STEPS + 1), lane);
    ACQ_FENCE();
    stage_data(ring1 + ((T_STEPS - 1) & 1) * HWW, lds_h0, tid);
    __syncthreads();
    if (w == 0) {
      const int obase = bx * 16;
      f32x4 a0, a1;
#pragma unroll
      for (int r = 0; r < 4; r++) {
        float bb = fcb[obase + 4 * q + r];
        a0[r] = bb; a1[r] = bb;
      }
      const float* Ar = fcw + (size_t)(obase + m) * HDIM + q8;
#pragma unroll
      for (int kc = 0; kc < 16; kc++) {
        short8 af = cvt8(Ar + kc * 32);
        short8 b0 = *(const short8*)(const void*)(lds_h0 + m * LROW + kc * 32 + q8);
        short8 b1 = *(const short8*)(const void*)(lds_h0 + (m + 16) * LROW + kc * 32 + q8);
        a0 = MFMA(af, b0, a0);
        a1 = MFMA(af, b1, a1);
      }
#pragma unroll
      for (int r = 0; r < 4; r++) {
        out[m * 256 + obase + 4 * q + r]        = a0[r];
        out[(m + 16) * 256 + obase + 4 * q + r] = a1[r];
      }
    }
  }
}

extern "C" void kernel_launch(void* const* d_in, const int* in_sizes, int n_in,
                              void* d_out, int out_size, void* d_ws, size_t ws_size,
                              hipStream_t stream) {
  const float* x    = (const float*)d_in[0];
  const float* Wih0 = (const float*)d_in[1];
  const float* Whh0 = (const float*)d_in[2];
  const float* bih0 = (const float*)d_in[3];
  const float* bhh0 = (const float*)d_in[4];
  const float* Wih1 = (const float*)d_in[5];
  const float* Whh1 = (const float*)d_in[6];
  const float* bih1 = (const float*)d_in[7];
  const float* bhh1 = (const float*)d_in[8];
  const float* fcw  = (const float*)d_in[9];
  const float* fcb  = (const float*)d_in[10];

  // ws: [0,128) combined flags (32 u32, one line); ring0 at 8K (4x32KB);
  // ring1 after (2x32KB). Ring data needs no init: validity gated by flags.
  u32* flg   = (u32*)d_ws;
  u32* ring0 = (u32*)((char*)d_ws + 8192);
  u32* ring1 = (u32*)((char*)d_ws + 8192 + (size_t)RS0 * HWW * sizeof(u32));

  hipMemsetAsync(d_ws, 0, 8192, stream);   // flags start at 0

  hipLaunchKernelGGL(lstm_fused, dim3(NBLK), dim3(256), 0, stream,
                     x, Wih0, Whh0, bih0, bhh0, Wih1, Whh1, bih1, bhh1, fcw, fcb,
                     (float*)d_out, flg, ring0, ring1);
}

// Round 5
// 9715.121 us; speedup vs baseline: 2.7936x; 2.7936x over previous
//
#include <hip/hip_runtime.h>
#include <hip/hip_bf16.h>

typedef __hip_bfloat16 bf16;
typedef unsigned long long u64;
typedef unsigned int u32;
typedef unsigned short u16;
using short8 = __attribute__((ext_vector_type(8))) short;   // 8 bf16 MFMA A/B frag
using f32x4  = __attribute__((ext_vector_type(4))) float;   // MFMA C/D frag

#define T_STEPS 2048
#define IDIM    256
#define HDIM    512
#define NBLK    128               // 2 pipelines x (32 L0-blocks + 32 L1-blocks)
#define R0      8                 // h0 ring slots per pipeline
#define HWW     8192              // u32 words per h buffer: [16 rows][512 units] tagged
#define LROW    528               // LDS row stride (bf16 elems)
#define TAGMASK 0x0000ffff0000ffffULL

__device__ __forceinline__ float sigm(float x) { return 1.0f / (1.0f + __expf(-x)); }
__device__ __forceinline__ float tanh_f(float x) {
  x = fminf(fmaxf(x, -15.f), 15.f);
  float e = __expf(2.f * x);
  return (e - 1.f) / (e + 1.f);
}
__device__ __forceinline__ u16 bfbits(float f) {
  bf16 b = __float2bfloat16(f); u16 s; __builtin_memcpy(&s, &b, 2); return s;
}
__device__ __forceinline__ short8 cvt8(const float* __restrict__ p) {
  float4 lo = *(const float4*)(const void*)p;
  float4 hi = *(const float4*)(const void*)(p + 4);
  short8 r;
  r[0] = (short)bfbits(lo.x); r[1] = (short)bfbits(lo.y); r[2] = (short)bfbits(lo.z); r[3] = (short)bfbits(lo.w);
  r[4] = (short)bfbits(hi.x); r[5] = (short)bfbits(hi.y); r[6] = (short)bfbits(hi.z); r[7] = (short)bfbits(hi.w);
  return r;
}

// LLC-coherent (L1/L2-bypassing) accesses: agent-scope relaxed atomics.
__device__ __forceinline__ u64 ldg8(const u64* p) {
  return __hip_atomic_load(p, __ATOMIC_RELAXED, __HIP_MEMORY_SCOPE_AGENT);
}
__device__ __forceinline__ u32 ldg4(const u32* p) {
  return __hip_atomic_load(p, __ATOMIC_RELAXED, __HIP_MEMORY_SCOPE_AGENT);
}
__device__ __forceinline__ void stg4(u32* p, u32 v) {
  __hip_atomic_store(p, v, __ATOMIC_RELAXED, __HIP_MEMORY_SCOPE_AGENT);
}

__device__ __forceinline__ int wave_min_i(int v) {
#pragma unroll
  for (int off = 32; off > 0; off >>= 1) {
    int o = __shfl_xor(v, off, 64);
    v = v < o ? v : o;
  }
  return v;
}

// Write one validated u64 chunk (2 tagged words, value in HIGH 16 bits) into LDS.
// chunk c = tid + i*256 -> row i, cols 2*tid, 2*tid+1.
__device__ __forceinline__ void ldsw(bf16* dst, int i, int tid, u64 v) {
  u32 lo = (u32)v, hi = (u32)(v >> 32);
  *(u32*)(void*)(dst + i * LROW + tid * 2) = (lo >> 16) | (hi & 0xffff0000u);
}

// Poll-stage one tagged 32KB h buffer -> LDS [16][LROW]. The loads ARE the sync:
// mask-parallel re-issue of any chunk whose epoch pair != tag. Tags in [1,2049];
// 0xAA poison / zeros never match.
__device__ __forceinline__ void pollstage(const u32* __restrict__ src, bf16* dst,
                                          int tid, u32 tag) {
  const u64* s = (const u64*)(const void*)src;
  const u64 tt = ((u64)tag << 32) | tag;
  u64 v[16];
#pragma unroll
  for (int i = 0; i < 16; i++) v[i] = ldg8(s + tid + i * 256);
  unsigned bad = 0xffffu;
  while (bad) {
    unsigned nb = 0;
#pragma unroll
    for (int i = 0; i < 16; i++)
      if (bad & (1u << i)) {
        if ((v[i] & TAGMASK) != tt) { v[i] = ldg8(s + tid + i * 256); nb |= 1u << i; }
      }
    bad = nb;
  }
#pragma unroll
  for (int i = 0; i < 16; i++) ldsw(dst, i, tid, v[i]);
}

// Poll-stage two tagged buffers concurrently (L1: h0[p] and h1[p-1], one merged wait).
__device__ __forceinline__ void poll2stage(const u32* __restrict__ s0p, bf16* d0, u32 tag0,
                                           const u32* __restrict__ s1p, bf16* d1, u32 tag1,
                                           int tid) {
  const u64* s0 = (const u64*)(const void*)s0p;
  const u64* s1 = (const u64*)(const void*)s1p;
  const u64 tt0 = ((u64)tag0 << 32) | tag0;
  const u64 tt1 = ((u64)tag1 << 32) | tag1;
  u64 v0[16], v1[16];
#pragma unroll
  for (int i = 0; i < 16; i++) v0[i] = ldg8(s0 + tid + i * 256);
#pragma unroll
  for (int i = 0; i < 16; i++) v1[i] = ldg8(s1 + tid + i * 256);
  unsigned bad0 = 0xffffu, bad1 = 0xffffu;
  while (bad0 | bad1) {
    unsigned nb0 = 0, nb1 = 0;
#pragma unroll
    for (int i = 0; i < 16; i++)
      if (bad0 & (1u << i)) {
        if ((v0[i] & TAGMASK) != tt0) { v0[i] = ldg8(s0 + tid + i * 256); nb0 |= 1u << i; }
      }
#pragma unroll
    for (int i = 0; i < 16; i++)
      if (bad1 & (1u << i)) {
        if ((v1[i] & TAGMASK) != tt1) { v1[i] = ldg8(s1 + tid + i * 256); nb1 |= 1u << i; }
      }
    bad0 = nb0; bad1 = nb1;
  }
#pragma unroll
  for (int i = 0; i < 16; i++) ldsw(d0, i, tid, v0[i]);
#pragma unroll
  for (int i = 0; i < 16; i++) ldsw(d1, i, tid, v1[i]);
}

#define MFMA(a, b, c) __builtin_amdgcn_mfma_f32_16x16x32_bf16((a), (b), (c), 0, 0, 0)

__global__ void __launch_bounds__(256, 1) lstm_tagged2p(
    const float* __restrict__ x,
    const float* __restrict__ Wih0, const float* __restrict__ Whh0,
    const float* __restrict__ bih0, const float* __restrict__ bhh0,
    const float* __restrict__ Wih1, const float* __restrict__ Whh1,
    const float* __restrict__ bih1, const float* __restrict__ bhh1,
    const float* __restrict__ fcw, const float* __restrict__ fcb,
    float* __restrict__ out,
    u32* __restrict__ ring0g,      // 2 pipelines x R0 x HWW tagged words (h0)
    u32* __restrict__ ring1g) {    // 2 pipelines x 2  x HWW (h1)
  __shared__ __align__(16) bf16 lds_h0[16 * LROW];
  __shared__ __align__(16) bf16 lds_h1[16 * LROW];

  const int tid  = threadIdx.x;
  const int w    = tid >> 6, lane = tid & 63;
  const int q    = lane >> 4, m = lane & 15, q8 = q * 8;
  const int bx   = (int)blockIdx.x;
  const int g    = bx >> 6;                 // pipeline = batch half (rows g*16..g*16+15)
  const int rr   = bx & 63;
  const bool l0  = (rr < 32);
  const int blk  = rr & 31;
  const int jb   = blk * 16 + w * 4;
  const int unit = jb + (m >> 2), gate = m & 3;
  const int wrow = gate * HDIM + unit;
  const int ju   = jb + q;
  const f32x4 zero = {0.f, 0.f, 0.f, 0.f};

  u32* ring0 = ring0g + (size_t)g * R0 * HWW;
  u32* ring1 = ring1g + (size_t)g * 2 * HWW;

  // ---- Preload weights (f32 -> bf16 A-frags) into VGPRs ----
  short8 A[32];
  f32x4 bias;
  if (l0) {
#pragma unroll
    for (int kc = 0; kc < 8; kc++)  A[kc]      = cvt8(Wih0 + wrow * IDIM + kc * 32 + q8);
#pragma unroll
    for (int kc = 0; kc < 16; kc++) A[8 + kc]  = cvt8(Whh0 + wrow * HDIM + kc * 32 + q8);
#pragma unroll
    for (int r = 0; r < 4; r++)
      bias[r] = bih0[r * HDIM + ju] + bhh0[r * HDIM + ju];
  } else {
#pragma unroll
    for (int kc = 0; kc < 16; kc++) A[kc]      = cvt8(Wih1 + wrow * HDIM + kc * 32 + q8);
#pragma unroll
    for (int kc = 0; kc < 16; kc++) A[16 + kc] = cvt8(Whh1 + wrow * HDIM + kc * 32 + q8);
#pragma unroll
    for (int r = 0; r < 4; r++)
      bias[r] = bih1[r * HDIM + ju] + bhh1[r * HDIM + ju];
  }

  float c_a = 0.f;

  if (l0) {
    // prefetch xg[0] for batch row g*16+m
    f32x4 an0 = bias;
    {
      const float* xa = x + (size_t)(g * 16 + m) * (T_STEPS * IDIM) + q8;
#pragma unroll
      for (int kc = 0; kc < 8; kc++) an0 = MFMA(A[kc], cvt8(xa + kc * 32), an0);
    }
    int est = R0 - 1;   // ring gate cache: h0 slot p%R0 writable for all p <= est
    for (int p = 0; p < T_STEPS; ++p) {
      f32x4 a0 = an0;                               // bias + Wih0 x[p]
      if (p > 0) {
        // Gather h0[p-1] — the poll IS the sync. Success also proves every L0
        // block stored h0[p-1], hence finished its LDS reads for step p-2; our
        // trailing barrier guards our own step p-1 reads.
        pollstage(ring0 + ((p - 1) & (R0 - 1)) * HWW, lds_h0, tid, (u32)p);
        __syncthreads();
        f32x4 b0 = zero;                            // dual deep-8 chains
#pragma unroll
        for (int kc = 0; kc < 8; kc++) {
          short8 r0 = *(const short8*)(const void*)(lds_h0 + m * LROW + kc * 32 + q8);
          a0 = MFMA(A[8 + kc], r0, a0);
          short8 s0 = *(const short8*)(const void*)(lds_h0 + m * LROW + (kc + 8) * 32 + q8);
          b0 = MFMA(A[16 + kc], s0, b0);
        }
        a0 = a0 + b0;
      }
      float ia = sigm(a0[0]), fa = sigm(a0[1]), ga = tanh_f(a0[2]), oa = sigm(a0[3]);
      c_a = fa * c_a + ia * ga;
      u32 word = ((u32)bfbits(oa * tanh_f(c_a)) << 16) | (u32)(p + 1);

      // Ring gate: slot p%R0 holds h0[p-R0]; overwrite safe once L1 finished step
      // p-R0+1's gather — proven by h1[p-R0] sentinel epochs (>= p-R0+1). Epochs
      // read as signed short: 0xAAAA poison is negative, never false-positive.
      if (p >= R0 && est < p) {
        int mn;
        do {
          u32 sw = ldg4(ring1 + (p & 1) * HWW + (lane & 31) * 16);
          mn = wave_min_i((int)(short)(sw & 0xffffu));
        } while (mn < p - (R0 - 1));
        est = mn + (R0 - 1);
      }
      stg4(ring0 + (p & (R0 - 1)) * HWW + (m << 9) + ju, word);   // no drain, no flag

      if (p + 1 < T_STEPS) {                        // prefetch xg[p+1] (off critical path)
        an0 = bias;
        const float* xa = x + (size_t)(g * 16 + m) * (T_STEPS * IDIM)
                        + (size_t)(p + 1) * IDIM + q8;
#pragma unroll
        for (int kc = 0; kc < 8; kc++) an0 = MFMA(A[kc], cvt8(xa + kc * 32), an0);
      }
      __syncthreads();   // own waves' LDS reads done before next stage overwrites
    }

    // ---- FC epilogue: blocks blk<16 of each pipeline do 16 out-cols x 16 rows ----
    if (blk < 16) {
      pollstage(ring1 + ((T_STEPS - 1) & 1) * HWW, lds_h0, tid, (u32)T_STEPS);
      __syncthreads();
      if (w == 0) {
        const int obase = blk * 16;
        f32x4 a0;
#pragma unroll
        for (int r = 0; r < 4; r++) a0[r] = fcb[obase + 4 * q + r];
        const float* Ar = fcw + (size_t)(obase + m) * HDIM + q8;
#pragma unroll
        for (int kc = 0; kc < 16; kc++) {
          short8 af = cvt8(Ar + kc * 32);
          short8 b0 = *(const short8*)(const void*)(lds_h0 + m * LROW + kc * 32 + q8);
          a0 = MFMA(af, b0, a0);
        }
#pragma unroll
        for (int r = 0; r < 4; r++)
          out[(size_t)(g * 16 + m) * 256 + obase + 4 * q + r] = a0[r];
      }
    }
  } else {
    // ---- layer 1: ONE merged poll (h0[p] + h1[p-1]), straight-line compute ----
    for (int p = 0; p < T_STEPS; ++p) {
      if (p == 0) {
        pollstage(ring0 + 0 * HWW, lds_h0, tid, 1u);
      } else {
        // Gathering h1[p-1] from ALL blocks also proves every L1 block finished
        // reading h1[p-2] (reads precede its stores) -> slot p&1 overwrite below
        // is race-free. Same argument keeps h0 ring reads safe.
        poll2stage(ring0 + (p & (R0 - 1)) * HWW, lds_h0, (u32)(p + 1),
                   ring1 + ((p - 1) & 1) * HWW,  lds_h1, (u32)p, tid);
      }
      __syncthreads();

      f32x4 c0 = bias, c1 = zero, c2 = zero, c3 = zero;   // 4 deep-8 chains
#pragma unroll
      for (int kc = 0; kc < 8; kc++) {
        short8 r0 = *(const short8*)(const void*)(lds_h0 + m * LROW + kc * 32 + q8);
        c0 = MFMA(A[kc], r0, c0);
        short8 s0 = *(const short8*)(const void*)(lds_h0 + m * LROW + (kc + 8) * 32 + q8);
        c1 = MFMA(A[8 + kc], s0, c1);
      }
      if (p > 0) {
#pragma unroll
        for (int kc = 0; kc < 8; kc++) {
          short8 r0 = *(const short8*)(const void*)(lds_h1 + m * LROW + kc * 32 + q8);
          c2 = MFMA(A[16 + kc], r0, c2);
          short8 s0 = *(const short8*)(const void*)(lds_h1 + m * LROW + (kc + 8) * 32 + q8);
          c3 = MFMA(A[24 + kc], s0, c3);
        }
      }
      f32x4 a0 = (c0 + c1) + (c2 + c3);
      float ia = sigm(a0[0]), fa = sigm(a0[1]), ga = tanh_f(a0[2]), oa = sigm(a0[3]);
      c_a = fa * c_a + ia * ga;
      u32 word = ((u32)bfbits(oa * tanh_f(c_a)) << 16) | (u32)(p + 1);
      stg4(ring1 + (p & 1) * HWW + (m << 9) + ju, word);          // no drain, no flag
      __syncthreads();   // LDS reads done before next iteration's staging overwrites
    }
  }
}

extern "C" void kernel_launch(void* const* d_in, const int* in_sizes, int n_in,
                              void* d_out, int out_size, void* d_ws, size_t ws_size,
                              hipStream_t stream) {
  const float* x    = (const float*)d_in[0];
  const float* Wih0 = (const float*)d_in[1];
  const float* Whh0 = (const float*)d_in[2];
  const float* bih0 = (const float*)d_in[3];
  const float* bhh0 = (const float*)d_in[4];
  const float* Wih1 = (const float*)d_in[5];
  const float* Whh1 = (const float*)d_in[6];
  const float* bih1 = (const float*)d_in[7];
  const float* bhh1 = (const float*)d_in[8];
  const float* fcw  = (const float*)d_in[9];
  const float* fcb  = (const float*)d_in[10];

  // ws: [0, 512K) h0 rings (2 pipelines x 8 x 32KB); [512K, 640K) h1 rings
  // (2 x 2 x 32KB). NO init needed: validity is per-word epoch tags; the
  // harness's 0xAA re-poison (epoch 0xAAAA) never matches tags in [1,2049]
  // and reads negative in the signed sentinel check.
  u32* ring0g = (u32*)d_ws;
  u32* ring1g = (u32*)((char*)d_ws + (size_t)2 * R0 * HWW * sizeof(u32));

  hipLaunchKernelGGL(lstm_tagged2p, dim3(NBLK), dim3(256), 0, stream,
                     x, Wih0, Whh0, bih0, bhh0, Wih1, Whh1, bih1, bhh1, fcw, fcb,
                     (float*)d_out, ring0g, ring1g);
}

// Round 6
// 8854.536 us; speedup vs baseline: 3.0652x; 1.0972x over previous
//
#include <hip/hip_runtime.h>
#include <hip/hip_bf16.h>

typedef __hip_bfloat16 bf16;
typedef unsigned long long u64;
typedef unsigned int u32;
typedef unsigned short u16;
using short8 = __attribute__((ext_vector_type(8))) short;   // 8 bf16 MFMA A/B frag
using f32x4  = __attribute__((ext_vector_type(4))) float;   // MFMA C/D frag

#define T_STEPS 2048
#define IDIM    256
#define HDIM    512
#define NBLK    128               // 2 pipelines x (32 L0-blocks + 32 L1-blocks)
#define R0      8                 // h0 ring slots per pipeline
#define HWW     8192              // u32 words per h buffer: [16 rows][512 units] tagged
#define LROW    528               // LDS row stride (bf16 elems)
#define TAGMASK 0x0000ffff0000ffffULL

__device__ __forceinline__ float sigm(float x) { return 1.0f / (1.0f + __expf(-x)); }
__device__ __forceinline__ float tanh_f(float x) {
  x = fminf(fmaxf(x, -15.f), 15.f);
  float e = __expf(2.f * x);
  return (e - 1.f) / (e + 1.f);
}
__device__ __forceinline__ u16 bfbits(float f) {
  bf16 b = __float2bfloat16(f); u16 s; __builtin_memcpy(&s, &b, 2); return s;
}
__device__ __forceinline__ short8 cvt8(const float* __restrict__ p) {
  float4 lo = *(const float4*)(const void*)p;
  float4 hi = *(const float4*)(const void*)(p + 4);
  short8 r;
  r[0] = (short)bfbits(lo.x); r[1] = (short)bfbits(lo.y); r[2] = (short)bfbits(lo.z); r[3] = (short)bfbits(lo.w);
  r[4] = (short)bfbits(hi.x); r[5] = (short)bfbits(hi.y); r[6] = (short)bfbits(hi.z); r[7] = (short)bfbits(hi.w);
  return r;
}

// LLC-coherent (L1/L2-bypassing) accesses: agent-scope relaxed atomics.
__device__ __forceinline__ u64 ldg8(const u64* p) {
  return __hip_atomic_load(p, __ATOMIC_RELAXED, __HIP_MEMORY_SCOPE_AGENT);
}
__device__ __forceinline__ u32 ldg4(const u32* p) {
  return __hip_atomic_load(p, __ATOMIC_RELAXED, __HIP_MEMORY_SCOPE_AGENT);
}
__device__ __forceinline__ void stg4(u32* p, u32 v) {
  __hip_atomic_store(p, v, __ATOMIC_RELAXED, __HIP_MEMORY_SCOPE_AGENT);
}

__device__ __forceinline__ int wave_min_i(int v) {
#pragma unroll
  for (int off = 32; off > 0; off >>= 1) {
    int o = __shfl_xor(v, off, 64);
    v = v < o ? v : o;
  }
  return v;
}

// Low-bandwidth readiness probe: 128 sentinel words = row-0 word of every
// producer WAVE (units 0,4,8,...,508). 2 ldg4/lane (~0.5KB/pass/wave) vs
// re-reading the full 32KB buffer -- this is what decontends the LLC.
// Equality check: tags in [1,2049]; 0xAA poison (0xAAAA) never matches.
__device__ __forceinline__ void probe_wait(const u32* __restrict__ slot, u32 tag, int lane) {
  const u32* p0 = slot + lane * 8;      // words lane*8 and lane*8+4: units 4k, row 0
  for (;;) {
    u32 a = ldg4(p0);
    u32 b = ldg4(p0 + 4);
    if (__all(((a & 0xffffu) == tag) && ((b & 0xffffu) == tag))) return;
  }
}

// Write one validated u64 chunk (2 tagged words, value in HIGH 16 bits) into LDS.
__device__ __forceinline__ void ldsw(bf16* dst, int i, int tid, u64 v) {
  u32 lo = (u32)v, hi = (u32)(v >> 32);
  *(u32*)(void*)(dst + i * LROW + tid * 2) = (lo >> 16) | (hi & 0xffff0000u);
}

// Bulk gather with tag validation (expected single-pass after probe_wait;
// the retry loop is the straggler safety net, keeping correctness independent
// of the probe's coverage).
__device__ __forceinline__ void gather(const u32* __restrict__ src, bf16* dst,
                                       int tid, u32 tag) {
  const u64* s = (const u64*)(const void*)src;
  const u64 tt = ((u64)tag << 32) | tag;
  u64 v[16];
#pragma unroll
  for (int i = 0; i < 16; i++) v[i] = ldg8(s + tid + i * 256);
  unsigned bad = 0xffffu;
  while (bad) {
    unsigned nb = 0;
#pragma unroll
    for (int i = 0; i < 16; i++)
      if (bad & (1u << i)) {
        if ((v[i] & TAGMASK) != tt) { v[i] = ldg8(s + tid + i * 256); nb |= 1u << i; }
      }
    bad = nb;
  }
#pragma unroll
  for (int i = 0; i < 16; i++) ldsw(dst, i, tid, v[i]);
}

#define MFMA(a, b, c) __builtin_amdgcn_mfma_f32_16x16x32_bf16((a), (b), (c), 0, 0, 0)

__global__ void __launch_bounds__(256, 1) lstm_probe2p(
    const float* __restrict__ x,
    const float* __restrict__ Wih0, const float* __restrict__ Whh0,
    const float* __restrict__ bih0, const float* __restrict__ bhh0,
    const float* __restrict__ Wih1, const float* __restrict__ Whh1,
    const float* __restrict__ bih1, const float* __restrict__ bhh1,
    const float* __restrict__ fcw, const float* __restrict__ fcb,
    float* __restrict__ out,
    u32* __restrict__ ring0g,      // 2 pipelines x R0 x HWW tagged words (h0)
    u32* __restrict__ ring1g) {    // 2 pipelines x 2  x HWW (h1)
  __shared__ __align__(16) bf16 lds_h0[16 * LROW];
  __shared__ __align__(16) bf16 lds_h1[16 * LROW];

  const int tid  = threadIdx.x;
  const int w    = tid >> 6, lane = tid & 63;
  const int q    = lane >> 4, m = lane & 15, q8 = q * 8;
  const int bx   = (int)blockIdx.x;
  const int g    = bx >> 6;                 // pipeline = batch half (rows g*16..g*16+15)
  const int rr   = bx & 63;
  const bool l0  = (rr < 32);
  const int blk  = rr & 31;
  const int jb   = blk * 16 + w * 4;
  const int unit = jb + (m >> 2), gate = m & 3;
  const int wrow = gate * HDIM + unit;
  const int ju   = jb + q;
  const f32x4 zero = {0.f, 0.f, 0.f, 0.f};

  u32* ring0 = ring0g + (size_t)g * R0 * HWW;
  u32* ring1 = ring1g + (size_t)g * 2 * HWW;

  // ---- Preload weights (f32 -> bf16 A-frags) into VGPRs ----
  short8 A[32];
  f32x4 bias;
  if (l0) {
#pragma unroll
    for (int kc = 0; kc < 8; kc++)  A[kc]      = cvt8(Wih0 + wrow * IDIM + kc * 32 + q8);
#pragma unroll
    for (int kc = 0; kc < 16; kc++) A[8 + kc]  = cvt8(Whh0 + wrow * HDIM + kc * 32 + q8);
#pragma unroll
    for (int r = 0; r < 4; r++)
      bias[r] = bih0[r * HDIM + ju] + bhh0[r * HDIM + ju];
  } else {
#pragma unroll
    for (int kc = 0; kc < 16; kc++) A[kc]      = cvt8(Wih1 + wrow * HDIM + kc * 32 + q8);
#pragma unroll
    for (int kc = 0; kc < 16; kc++) A[16 + kc] = cvt8(Whh1 + wrow * HDIM + kc * 32 + q8);
#pragma unroll
    for (int r = 0; r < 4; r++)
      bias[r] = bih1[r * HDIM + ju] + bhh1[r * HDIM + ju];
  }

  float c_a = 0.f;

  if (l0) {
    // prefetch xg[0] for batch row g*16+m
    f32x4 an0 = bias;
    {
      const float* xa = x + (size_t)(g * 16 + m) * (T_STEPS * IDIM) + q8;
#pragma unroll
      for (int kc = 0; kc < 8; kc++) an0 = MFMA(A[kc], cvt8(xa + kc * 32), an0);
    }
    int est = R0 - 1;   // ring gate cache: h0 slot p%R0 writable for all p <= est
    for (int p = 0; p < T_STEPS; ++p) {
      f32x4 a0 = an0;                               // bias + Wih0 x[p]
      if (p > 0) {
        // Cheap sentinel probe, then one-pass validated gather of h0[p-1].
        probe_wait(ring0 + ((p - 1) & (R0 - 1)) * HWW, (u32)p, lane);
        gather(ring0 + ((p - 1) & (R0 - 1)) * HWW, lds_h0, tid, (u32)p);
        __syncthreads();
        f32x4 b0 = zero;                            // dual deep-8 chains
#pragma unroll
        for (int kc = 0; kc < 8; kc++) {
          short8 r0 = *(const short8*)(const void*)(lds_h0 + m * LROW + kc * 32 + q8);
          a0 = MFMA(A[8 + kc], r0, a0);
          short8 s0 = *(const short8*)(const void*)(lds_h0 + m * LROW + (kc + 8) * 32 + q8);
          b0 = MFMA(A[16 + kc], s0, b0);
        }
        a0 = a0 + b0;
      }
      float ia = sigm(a0[0]), fa = sigm(a0[1]), ga = tanh_f(a0[2]), oa = sigm(a0[3]);
      c_a = fa * c_a + ia * ga;
      u32 word = ((u32)bfbits(oa * tanh_f(c_a)) << 16) | (u32)(p + 1);

      // Ring gate: slot p%R0 holds h0[p-R0]; overwrite safe once every L1 block
      // finished step p-R0 (its wave-0 h1 sentinel epoch >= p-R0+1 proves its
      // whole block's gather of h0[p-R0] completed: the store follows the
      // block's gather barrier). Signed cast: 0xAAAA poison reads negative.
      if (p >= R0 && est < p) {
        int mn;
        do {
          u32 sw = ldg4(ring1 + (p & 1) * HWW + (lane & 31) * 16);
          mn = wave_min_i((int)(short)(sw & 0xffffu));
        } while (mn < p - (R0 - 1));
        est = mn + (R0 - 1);
      }
      stg4(ring0 + (p & (R0 - 1)) * HWW + (m << 9) + ju, word);   // no drain, no flag

      if (p + 1 < T_STEPS) {                        // prefetch xg[p+1] (off critical path)
        an0 = bias;
        const float* xa = x + (size_t)(g * 16 + m) * (T_STEPS * IDIM)
                        + (size_t)(p + 1) * IDIM + q8;
#pragma unroll
        for (int kc = 0; kc < 8; kc++) an0 = MFMA(A[kc], cvt8(xa + kc * 32), an0);
      }
      __syncthreads();   // own waves' LDS reads done before next stage overwrites
    }

    // ---- FC epilogue: blocks blk<16 of each pipeline do 16 out-cols x 16 rows ----
    if (blk < 16) {
      probe_wait(ring1 + ((T_STEPS - 1) & 1) * HWW, (u32)T_STEPS, lane);
      gather(ring1 + ((T_STEPS - 1) & 1) * HWW, lds_h0, tid, (u32)T_STEPS);
      __syncthreads();
      if (w == 0) {
        const int obase = blk * 16;
        f32x4 a0;
#pragma unroll
        for (int r = 0; r < 4; r++) a0[r] = fcb[obase + 4 * q + r];
        const float* Ar = fcw + (size_t)(obase + m) * HDIM + q8;
#pragma unroll
        for (int kc = 0; kc < 16; kc++) {
          short8 af = cvt8(Ar + kc * 32);
          short8 b0 = *(const short8*)(const void*)(lds_h0 + m * LROW + kc * 32 + q8);
          a0 = MFMA(af, b0, a0);
        }
#pragma unroll
        for (int r = 0; r < 4; r++)
          out[(size_t)(g * 16 + m) * 256 + obase + 4 * q + r] = a0[r];
      }
    }
  } else {
    // ---- layer 1: h0 early (L0 runs ~R0 ahead -> instant), h1 late.
    //      The Wih1 half runs INSIDE the window where peers publish h1[p-1].
    for (int p = 0; p < T_STEPS; ++p) {
      probe_wait(ring0 + (p & (R0 - 1)) * HWW, (u32)(p + 1), lane);
      gather(ring0 + (p & (R0 - 1)) * HWW, lds_h0, tid, (u32)(p + 1));
      __syncthreads();                         // barrier A: lds_h0 staged

      f32x4 c0 = bias, c1 = zero, c2 = zero, c3 = zero;   // 4 deep-8 chains
#pragma unroll
      for (int kc = 0; kc < 8; kc++) {
        short8 r0 = *(const short8*)(const void*)(lds_h0 + m * LROW + kc * 32 + q8);
        c0 = MFMA(A[kc], r0, c0);
        short8 s0 = *(const short8*)(const void*)(lds_h0 + m * LROW + (kc + 8) * 32 + q8);
        c1 = MFMA(A[8 + kc], s0, c1);
      }
      if (p > 0) {
        // h1[p-1] recurrence gate: probe (cheap) then one-pass gather.
        probe_wait(ring1 + ((p - 1) & 1) * HWW, (u32)p, lane);
        gather(ring1 + ((p - 1) & 1) * HWW, lds_h1, tid, (u32)p);
        __syncthreads();                       // barrier B: lds_h1 staged
#pragma unroll
        for (int kc = 0; kc < 8; kc++) {
          short8 r0 = *(const short8*)(const void*)(lds_h1 + m * LROW + kc * 32 + q8);
          c2 = MFMA(A[16 + kc], r0, c2);
          short8 s0 = *(const short8*)(const void*)(lds_h1 + m * LROW + (kc + 8) * 32 + q8);
          c3 = MFMA(A[24 + kc], s0, c3);
        }
      }
      f32x4 a0 = (c0 + c1) + (c2 + c3);
      float ia = sigm(a0[0]), fa = sigm(a0[1]), ga = tanh_f(a0[2]), oa = sigm(a0[3]);
      c_a = fa * c_a + ia * ga;
      u32 word = ((u32)bfbits(oa * tanh_f(c_a)) << 16) | (u32)(p + 1);
      stg4(ring1 + (p & 1) * HWW + (m << 9) + ju, word);          // no drain, no flag
      // LDS reuse safety without a trailing barrier (p>0): next iter's lds_h0
      // write requires passing next barrier A, which every wave reaches only
      // after THIS step's Wih1 reads; next iter's lds_h1 write requires passing
      // next barrier A too, which follows this step's Whh1 reads. p==0 has no
      // barrier B, so close the loop explicitly:
      if (p == 0) __syncthreads();
    }
  }
}

extern "C" void kernel_launch(void* const* d_in, const int* in_sizes, int n_in,
                              void* d_out, int out_size, void* d_ws, size_t ws_size,
                              hipStream_t stream) {
  const float* x    = (const float*)d_in[0];
  const float* Wih0 = (const float*)d_in[1];
  const float* Whh0 = (const float*)d_in[2];
  const float* bih0 = (const float*)d_in[3];
  const float* bhh0 = (const float*)d_in[4];
  const float* Wih1 = (const float*)d_in[5];
  const float* Whh1 = (const float*)d_in[6];
  const float* bih1 = (const float*)d_in[7];
  const float* bhh1 = (const float*)d_in[8];
  const float* fcw  = (const float*)d_in[9];
  const float* fcb  = (const float*)d_in[10];

  // ws: [0, 512K) h0 rings (2 pipelines x 8 x 32KB); [512K, 640K) h1 rings
  // (2 x 2 x 32KB). NO init needed: validity is per-word epoch tags; the
  // harness's 0xAA re-poison (epoch 0xAAAA) never matches tags in [1,2049]
  // and reads negative in the signed sentinel check.
  u32* ring0g = (u32*)d_ws;
  u32* ring1g = (u32*)((char*)d_ws + (size_t)2 * R0 * HWW * sizeof(u32));

  hipLaunchKernelGGL(lstm_probe2p, dim3(NBLK), dim3(256), 0, stream,
                     x, Wih0, Whh0, bih0, bhh0, Wih1, Whh1, bih1, bhh1, fcw, fcb,
                     (float*)d_out, ring0g, ring1g);
}